// Round 1
// baseline (364.952 us; speedup 1.0000x reference)
//
#include <hip/hip_runtime.h>
#include <math.h>

#define PI_F 3.14159265358979323846f
#define BB 2
#define LL 1024
#define NCH 64
#define CHUNK 32
#define NCHUNK (LL/CHUNK)
#define NW 1408          // Wb rows: 512 Wv | 256 Wg1 | 16 Wk | 16 Wq | 96 pad0 | 512 Wo
#define YH 384           // Yh cols: 256 h | 16 kp | 16 qp | 96 pad
#define GRID_F 512

typedef __attribute__((ext_vector_type(8))) short short8;
typedef __attribute__((ext_vector_type(4))) float floatx4;
typedef const __attribute__((address_space(1))) unsigned int cgu32;
typedef __attribute__((address_space(3))) unsigned int lu32;

__device__ __forceinline__ unsigned short f2bf(float f){
    unsigned u = __float_as_uint(f);
    unsigned r = (u + 0x7fff + ((u >> 16) & 1)) >> 16;   // RNE
    return (unsigned short)r;
}

// ---- prep: weights -> bf16 Wb[n][k], bcat; x -> bf16 xb; zero barrier ctrs ----
__global__ __launch_bounds__(128) void k_prep(
    const float* __restrict__ Wv, const float* __restrict__ Wg1,
    const float* __restrict__ Wk, const float* __restrict__ Wq,
    const float* __restrict__ Wo,
    const float* __restrict__ bv, const float* __restrict__ bg1,
    const float* __restrict__ bk, const float* __restrict__ bq,
    const float* __restrict__ bo, const float* __restrict__ x,
    unsigned short* __restrict__ Wb, float* __restrict__ bcat,
    unsigned short* __restrict__ xb, unsigned* __restrict__ bar)
{
    const int bid = blockIdx.x, tid = threadIdx.x;
    if (bid == 0 && tid < 8) bar[tid] = 0u;
    if (bid < NW){
        const int n = bid;
        const float* src = (n<512) ? Wv  + (size_t)n*512
                         : (n<768) ? Wg1 + (size_t)(n-512)*512
                         : (n<784) ? Wk  + (size_t)(n-768)*512
                         : (n<800) ? Wq  + (size_t)(n-784)*512
                         : (n<896) ? (const float*)0
                                   : Wo  + (size_t)(n-896)*512;
        float4 v = make_float4(0.f,0.f,0.f,0.f);
        if (src) v = ((const float4*)src)[tid];
        ushort4 o; o.x=f2bf(v.x); o.y=f2bf(v.y); o.z=f2bf(v.z); o.w=f2bf(v.w);
        ((ushort4*)(Wb + (size_t)n*512))[tid] = o;
        if (tid == 0)
            bcat[n] = (n<512)?bv[n] : (n<768)?bg1[n-512] : (n<784)?bk[n-768]
                    : (n<800)?bq[n-784] : (n<896)?0.f : bo[n-896];
    } else {
        const size_t i = (size_t)(bid - NW)*128 + tid;    // float4 index
        float4 v = ((const float4*)x)[i];
        ushort4 o; o.x=f2bf(v.x); o.y=f2bf(v.y); o.z=f2bf(v.z); o.w=f2bf(v.w);
        ((ushort4*)xb)[i] = o;
    }
}

// ---- device-wide barrier (co-residency guaranteed: grid 512 = 2 blocks/CU) ----
__device__ __forceinline__ void gsync(unsigned* bar, unsigned nblk){
    __syncthreads();
    if (threadIdx.x == 0){
        __threadfence();   // release: push this block's writes to coherence point
        __hip_atomic_fetch_add(bar, 1u, __ATOMIC_RELAXED, __HIP_MEMORY_SCOPE_AGENT);
        while (__hip_atomic_load(bar, __ATOMIC_RELAXED, __HIP_MEMORY_SCOPE_AGENT) < nblk)
            __builtin_amdgcn_s_sleep(2);
        __threadfence();   // acquire: invalidate stale cached lines
    }
    __syncthreads();
}

// ---- MFMA 64x64x512 tile core (verified) ----
__device__ __forceinline__ void gemm64x64(
    const unsigned short* Ag, const unsigned short* Bg,
    short* As, short* Bs, int tid, floatx4 acc[2][2])
{
    const int lane = tid & 63, w = tid >> 6;
    const int q = lane >> 4, m15 = lane & 15;
    for (int kt = 0; kt < 512; kt += 64) {
        __syncthreads();
        #pragma unroll
        for (int i = 0; i < 2; ++i) {
            const int rowbase = (w*2 + i) * 8;
            const int r  = rowbase + (lane >> 3);
            const int gb = (lane & 7) ^ (r & 7);
            const unsigned short* ga  = Ag + (size_t)r*512 + kt + gb*8;
            const unsigned short* gbp = Bg + (size_t)r*512 + kt + gb*8;
            __builtin_amdgcn_global_load_lds((cgu32*)(const void*)ga,
                                             (lu32*)(As + rowbase*64), 16, 0, 0);
            __builtin_amdgcn_global_load_lds((cgu32*)(const void*)gbp,
                                             (lu32*)(Bs + rowbase*64), 16, 0, 0);
        }
        __syncthreads();
        #pragma unroll
        for (int k32 = 0; k32 < 64; k32 += 32) {
            short8 af[2], bf[2];
            #pragma unroll
            for (int t = 0; t < 2; ++t) {
                const int ra  = 32*(w & 1) + 16*t + m15;
                const int sba = ((k32>>3) + q) ^ (ra & 7);
                af[t] = *(const short8*)(As + ra*64 + sba*8);
                const int rb  = 32*(w >> 1) + 16*t + m15;
                const int sbb = ((k32>>3) + q) ^ (rb & 7);
                bf[t] = *(const short8*)(Bs + rb*64 + sbb*8);
            }
            #pragma unroll
            for (int mt = 0; mt < 2; ++mt)
                #pragma unroll
                for (int nt = 0; nt < 2; ++nt)
                    acc[mt][nt] = __builtin_amdgcn_mfma_f32_16x16x32_bf16(
                        af[mt], bf[nt], acc[mt][nt], 0, 0, 0);
        }
    }
}

// ---- fused: GEMM1 -> act -> chunk sums -> prefix -> scan+LN -> GEMM2 ----
__global__ __launch_bounds__(256, 2) void k_fused(
    const unsigned short* __restrict__ xb, const unsigned short* __restrict__ Wb,
    const float* __restrict__ bcat, unsigned short* __restrict__ Vt,
    float* __restrict__ Yh,
    const float* __restrict__ Wg2, const float* __restrict__ bg2,
    const float* __restrict__ set_w, const float* __restrict__ pos_phases,
    const float* __restrict__ pos_weight,
    unsigned short* __restrict__ ab, unsigned short* __restrict__ Rb,
    unsigned short* __restrict__ aT,
    float* __restrict__ P, unsigned short* __restrict__ S0t,
    const float* __restrict__ ln_g, const float* __restrict__ ln_b,
    unsigned short* __restrict__ Tn,
    const float* __restrict__ x, float* __restrict__ out,
    unsigned* __restrict__ bar)
{
    __shared__ __align__(16) char smem[67584];   // max(As+Bs=16K, Msh+Tsh=66K)
    const int bid = blockIdx.x, tid = threadIdx.x;
    const int lane = tid & 63, w = tid >> 6;
    const int q = lane >> 4, m15 = lane & 15;

    // ================= phase 1: GEMM1 (448 tiles) =================
    if (bid < 448){
        short* As = (short*)smem;
        short* Bs = (short*)(smem + 8192);
        const int row0 = (bid & 31)*64, n0 = (bid >> 5)*64;
        floatx4 acc[2][2];
        #pragma unroll
        for (int mt=0;mt<2;++mt)
            #pragma unroll
            for (int nt=0;nt<2;++nt) acc[mt][nt] = (floatx4){0.f,0.f,0.f,0.f};
        gemm64x64(xb + (size_t)row0*512, Wb + (size_t)n0*512, As, Bs, tid, acc);
        const int wm = w & 1, wn = w >> 1;
        if (n0 < 512){
            const int b = row0 >> 10, lb = row0 & 1023;
            #pragma unroll
            for (int mt=0;mt<2;++mt)
                #pragma unroll
                for (int nt=0;nt<2;++nt){
                    const int d = n0 + 32*wn + 16*nt + m15;
                    const float bb = bcat[d];
                    const int l0 = lb + 32*wm + 16*mt + q*4;
                    ushort4 o;
                    o.x = f2bf(acc[mt][nt][0] + bb);
                    o.y = f2bf(acc[mt][nt][1] + bb);
                    o.z = f2bf(acc[mt][nt][2] + bb);
                    o.w = f2bf(acc[mt][nt][3] + bb);
                    *(ushort4*)(Vt + ((size_t)(b*512 + d))*1024 + l0) = o;
                }
        } else {
            #pragma unroll
            for (int mt=0;mt<2;++mt)
                #pragma unroll
                for (int nt=0;nt<2;++nt){
                    const int n = n0 + 32*wn + 16*nt + m15;
                    const float bb = bcat[n];
                    #pragma unroll
                    for (int reg=0;reg<4;++reg){
                        const int m = row0 + 32*wm + 16*mt + q*4 + reg;
                        Yh[(size_t)m*YH + (n-512)] = acc[mt][nt][reg] + bb;
                    }
                }
        }
    }
    gsync(bar+0, GRID_F);

    // ================= phase 2: activations (4 rows/block) =================
    {
        float s0=set_w[0], s1=set_w[1], s2=set_w[2], s3=set_w[3];
        float mm = fmaxf(fmaxf(s0,s1), fmaxf(s2,s3));
        float e0=expf(s0-mm), e1=expf(s1-mm), e2=expf(s2-mm), e3=expf(s3-mm);
        float esum = e0+e1+e2+e3;
        float spw = 1.f/(1.f+expf(-pos_weight[0]));
        float b2 = bg2[0];
        const int row = bid*4 + w;
        const float* yrow = Yh + (size_t)row*YH;
        float hs = 0.f;
        #pragma unroll
        for (int i=0;i<4;++i){
            float hv = yrow[lane + 64*i];
            float ge = 0.5f*hv*(1.f + erff(hv*0.70710678118f));
            hs += ge * Wg2[lane + 64*i];
        }
        #pragma unroll
        for (int off=32; off; off>>=1) hs += __shfl_xor(hs, off, 64);
        float g = 1.f/(1.f+expf(-(hs + b2)));
        if (lane < 16){
            int j = lane;
            int l = row & (LL-1);
            int b = row >> 10;
            float kang = PI_F*tanhf(yrow[256 + j]);
            float qang = PI_F*tanhf(yrow[272 + j]);
            float wsm = (j<4?e0: j<8?e1: j<12?e2: e3) / esum;
            float rnorm = 1.f/(2.f*sqrtf((float)(l+1)));
            float av[4], rv[4];
            av[0] = cosf(kang); av[1] = sinf(kang);
            float cw = g*wsm*rnorm;
            rv[0] = cw*cosf(qang); rv[1] = cw*sinf(qang);
            float ph = pos_phases[(size_t)l*16 + j];
            float pc = cosf(ph), ps = sinf(ph);
            av[2] = pc; av[3] = ps;
            float cp = (1.f-g)*spw*rnorm;
            rv[2] = cp*pc; rv[3] = cp*ps;
            unsigned short* arow = ab + (size_t)row*NCH;
            unsigned short* Rrow = Rb + (size_t)row*NCH;
            #pragma unroll
            for (int t=0;t<4;++t){
                arow[16*t + j] = f2bf(av[t]);
                Rrow[16*t + j] = f2bf(rv[t]);
                aT[((size_t)b*NCH + 16*t + j)*1024 + l] = f2bf(av[t]);
            }
        }
    }
    gsync(bar+1, GRID_F);

    // ================= phase 3: chunk sums (all 512 blocks, d split 8-way) ===
    {
        const int c = bid & 31, b = (bid >> 5) & 1, z8 = bid >> 6;
        short8 af[4];
        #pragma unroll
        for (int mt=0;mt<4;++mt)
            af[mt] = *(const short8*)(aT + ((size_t)b*NCH + 16*mt + m15)*1024 + c*32 + q*8);
        const int d = z8*64 + w*16 + m15;
        short8 bf = *(const short8*)(Vt + ((size_t)(b*512 + d))*1024 + c*32 + q*8);
        floatx4 pacc[4];
        #pragma unroll
        for (int mt=0;mt<4;++mt) pacc[mt] = (floatx4){0.f,0.f,0.f,0.f};
        #pragma unroll
        for (int mt=0;mt<4;++mt)
            pacc[mt] = __builtin_amdgcn_mfma_f32_16x16x32_bf16(af[mt], bf, pacc[mt], 0,0,0);
        float* Pc = P + ((size_t)(b*NCHUNK + c))*512*NCH;
        #pragma unroll
        for (int mt=0;mt<4;++mt)
            *(floatx4*)(Pc + (size_t)d*NCH + 16*mt + q*4) = pacc[mt];
    }
    gsync(bar+2, GRID_F);

    // ================= phase 4: exclusive prefix over chunks =================
    if (bid < 256){
        const int b = bid >> 7;
        const size_t idx = (size_t)(bid & 127)*256 + tid;   // over 512*64
        float run = 0.f;
        for (int c2=0;c2<NCHUNK;++c2){
            const size_t o = ((size_t)(b*NCHUNK + c2))*512*NCH + idx;
            float v = P[o];
            S0t[o] = f2bf(run);
            run += v;
        }
    }
    gsync(bar+3, GRID_F);

    // ================= phase 5: within-chunk scan + LN =================
    if (bid < 64){
        short* Msh = (short*)smem;            // 32*32 shorts
        float* Tsh = (float*)(smem + 2048);   // 32*512 floats
        const int c = bid & 31, b = bid >> 5;
        const int grow = b*1024 + c*32;

        if (w == 0){                       // wave 0 computes M = tril(R @ a^T)
            floatx4 mcc[2][2];
            #pragma unroll
            for (int mt=0;mt<2;++mt)
                #pragma unroll
                for (int nt=0;nt<2;++nt) mcc[mt][nt] = (floatx4){0.f,0.f,0.f,0.f};
            #pragma unroll
            for (int ks=0;ks<2;++ks){
                short8 ra[2], bb[2];
                #pragma unroll
                for (int t=0;t<2;++t){
                    ra[t] = *(const short8*)(Rb + (size_t)(grow + 16*t + m15)*NCH + ks*32 + q*8);
                    bb[t] = *(const short8*)(ab + (size_t)(grow + 16*t + m15)*NCH + ks*32 + q*8);
                }
                #pragma unroll
                for (int mt=0;mt<2;++mt)
                    #pragma unroll
                    for (int nt=0;nt<2;++nt)
                        mcc[mt][nt] = __builtin_amdgcn_mfma_f32_16x16x32_bf16(
                            ra[mt], bb[nt], mcc[mt][nt], 0,0,0);
            }
            #pragma unroll
            for (int mt=0;mt<2;++mt)
                #pragma unroll
                for (int nt=0;nt<2;++nt){
                    const int nl = 16*nt + m15;
                    #pragma unroll
                    for (int reg=0;reg<4;++reg){
                        const int ml = 16*mt + q*4 + reg;
                        Msh[ml*32 + nl] = (nl <= ml) ? (short)f2bf(mcc[mt][nt][reg]) : (short)0;
                    }
                }
        }
        __syncthreads();

        short8 a1[2], a2[2][2];
        #pragma unroll
        for (int mt=0;mt<2;++mt){
            a1[mt] = *(const short8*)(Msh + (16*mt + m15)*32 + q*8);
            #pragma unroll
            for (int ks=0;ks<2;++ks)
                a2[ks][mt] = *(const short8*)(Rb + (size_t)(grow + 16*mt + m15)*NCH + ks*32 + q*8);
        }
        floatx4 acc[2][8];
        #pragma unroll
        for (int mt=0;mt<2;++mt)
            #pragma unroll
            for (int nt=0;nt<8;++nt) acc[mt][nt] = (floatx4){0.f,0.f,0.f,0.f};
        const unsigned short* S0c = S0t + ((size_t)(b*NCHUNK + c))*512*NCH;
        #pragma unroll
        for (int nt=0;nt<8;++nt){
            const int d = w*128 + 16*nt + m15;
            short8 b1 = *(const short8*)(Vt + ((size_t)(b*512 + d))*1024 + c*32 + q*8);
            #pragma unroll
            for (int mt=0;mt<2;++mt)
                acc[mt][nt] = __builtin_amdgcn_mfma_f32_16x16x32_bf16(a1[mt], b1, acc[mt][nt], 0,0,0);
            #pragma unroll
            for (int ks=0;ks<2;++ks){
                short8 b2v = *(const short8*)(S0c + (size_t)d*NCH + ks*32 + q*8);
                #pragma unroll
                for (int mt=0;mt<2;++mt)
                    acc[mt][nt] = __builtin_amdgcn_mfma_f32_16x16x32_bf16(a2[ks][mt], b2v, acc[mt][nt], 0,0,0);
            }
        }
        #pragma unroll
        for (int mt=0;mt<2;++mt)
            #pragma unroll
            for (int nt=0;nt<8;++nt){
                const int d = w*128 + 16*nt + m15;
                #pragma unroll
                for (int reg=0;reg<4;++reg)
                    Tsh[(16*mt + q*4 + reg)*512 + d] = acc[mt][nt][reg];
            }
        __syncthreads();

        // LN per row (wave handles 8 rows), write Tn bf16 row-major
        #pragma unroll
        for (int i=0;i<8;++i){
            const int r = w*8 + i;
            float s=0.f, sq=0.f;
            #pragma unroll
            for (int t=0;t<8;++t){
                float v = Tsh[r*512 + lane + 64*t];
                s += v; sq += v*v;
            }
            #pragma unroll
            for (int off=32; off; off>>=1){
                s += __shfl_xor(s, off, 64); sq += __shfl_xor(sq, off, 64);
            }
            float mu  = s*(1.f/512.f);
            float var = sq*(1.f/512.f) - mu*mu;
            float rsd = rsqrtf(var + 1e-5f);
            unsigned short* trow = Tn + (size_t)(grow + r)*512;
            #pragma unroll
            for (int t=0;t<8;++t){
                const int d = lane + 64*t;
                float v = (Tsh[r*512 + d] - mu)*rsd*ln_g[d] + ln_b[d];
                trow[d] = f2bf(v);
            }
        }
    }
    gsync(bar+4, GRID_F);

    // ================= phase 6: GEMM2 (256 tiles) =================
    if (bid < 256){
        short* As = (short*)smem;
        short* Bs = (short*)(smem + 8192);
        const int row0 = (bid & 31)*64, n0 = (bid >> 5)*64;
        floatx4 acc[2][2];
        #pragma unroll
        for (int mt=0;mt<2;++mt)
            #pragma unroll
            for (int nt=0;nt<2;++nt) acc[mt][nt] = (floatx4){0.f,0.f,0.f,0.f};
        gemm64x64(Tn + (size_t)row0*512, Wb + (size_t)(896+n0)*512, As, Bs, tid, acc);
        const int wm = w & 1, wn = w >> 1;
        #pragma unroll
        for (int mt=0;mt<2;++mt)
            #pragma unroll
            for (int nt=0;nt<2;++nt){
                const int n = n0 + 32*wn + 16*nt + m15;
                const float bb = bcat[896 + n];
                #pragma unroll
                for (int reg=0;reg<4;++reg){
                    const int m = row0 + 32*wm + 16*mt + q*4 + reg;
                    out[(size_t)m*512 + n] = x[(size_t)m*512 + n] + acc[mt][nt][reg] + bb;
                }
            }
    }
}

extern "C" void kernel_launch(void* const* d_in, const int* in_sizes, int n_in,
                              void* d_out, int out_size, void* d_ws, size_t ws_size,
                              hipStream_t stream) {
    const float* x    = (const float*)d_in[0];
    const float* Wk   = (const float*)d_in[1];
    const float* bk   = (const float*)d_in[2];
    const float* Wq   = (const float*)d_in[3];
    const float* bq   = (const float*)d_in[4];
    const float* Wv   = (const float*)d_in[5];
    const float* bv   = (const float*)d_in[6];
    const float* ln_g = (const float*)d_in[7];
    const float* ln_b = (const float*)d_in[8];
    const float* Wo   = (const float*)d_in[9];
    const float* bo   = (const float*)d_in[10];
    const float* set_w      = (const float*)d_in[11];
    const float* pos_phases = (const float*)d_in[12];
    const float* pos_weight = (const float*)d_in[13];
    const float* Wg1  = (const float*)d_in[14];
    const float* bg1  = (const float*)d_in[15];
    const float* Wg2  = (const float*)d_in[16];
    const float* bg2  = (const float*)d_in[17];
    float* out = (float*)d_out;

    // workspace: fp32 region, then bf16 region (~24 MB), then barrier ctrs
    float* ws   = (float*)d_ws;
    float* Yh   = ws;                                     // 2048*384
    float* P    = Yh + (size_t)2048*YH;                   // 2*32*512*64
    float* bcat = P  + (size_t)BB*NCHUNK*512*NCH;         // 1408
    unsigned short* Wb  = (unsigned short*)(bcat + NW);   // 1408*512
    unsigned short* xb  = Wb  + (size_t)NW*512;           // 2048*512
    unsigned short* Vt  = xb  + (size_t)2048*512;         // 2*512*1024
    unsigned short* ab  = Vt  + (size_t)BB*512*1024;      // 2048*64
    unsigned short* Rb  = ab  + (size_t)2048*NCH;         // 2048*64
    unsigned short* aT  = Rb  + (size_t)2048*NCH;         // 2*64*1024
    unsigned short* S0t = aT  + (size_t)BB*NCH*1024;      // 2*32*512*64
    unsigned short* Tn  = S0t + (size_t)BB*NCHUNK*512*NCH;// 2048*512
    unsigned*       bar = (unsigned*)(Tn + (size_t)2048*512); // 8 ctrs

    k_prep<<<dim3(NW + 2048), 128, 0, stream>>>(
        Wv,Wg1,Wk,Wq,Wo, bv,bg1,bk,bq,bo, x, Wb, bcat, xb, bar);
    k_fused<<<dim3(GRID_F), 256, 0, stream>>>(
        xb, Wb, bcat, Vt, Yh, Wg2, bg2, set_w, pos_phases, pos_weight,
        ab, Rb, aT, P, S0t, ln_g, ln_b, Tn, x, out, bar);
}

// Round 2
// 200.048 us; speedup vs baseline: 1.8243x; 1.8243x over previous
//
#include <hip/hip_runtime.h>
#include <math.h>

#define PI_F 3.14159265358979323846f
#define BB 2
#define LL 1024
#define NCH 64
#define CHUNK 32
#define NCHUNK (LL/CHUNK)
#define NW 1408          // Wb rows: 512 Wv | 256 Wg1 | 16 Wk | 16 Wq | 96 pad0 | 512 Wo
#define YH 384           // Yh cols: 256 h | 16 kp | 16 qp | 96 pad
#define GRID_F 512

typedef __attribute__((ext_vector_type(8))) short short8;
typedef __attribute__((ext_vector_type(4))) float floatx4;
typedef const __attribute__((address_space(1))) unsigned int cgu32;
typedef __attribute__((address_space(3))) unsigned int lu32;

__device__ __forceinline__ unsigned short f2bf(float f){
    unsigned u = __float_as_uint(f);
    unsigned r = (u + 0x7fff + ((u >> 16) & 1)) >> 16;   // RNE
    return (unsigned short)r;
}

// ---- prep: weights -> bf16 Wb[n][k], bcat; x -> bf16 xb; zero barrier ctrs ----
__global__ __launch_bounds__(128) void k_prep(
    const float* __restrict__ Wv, const float* __restrict__ Wg1,
    const float* __restrict__ Wk, const float* __restrict__ Wq,
    const float* __restrict__ Wo,
    const float* __restrict__ bv, const float* __restrict__ bg1,
    const float* __restrict__ bk, const float* __restrict__ bq,
    const float* __restrict__ bo, const float* __restrict__ x,
    unsigned short* __restrict__ Wb, float* __restrict__ bcat,
    unsigned short* __restrict__ xb, unsigned* __restrict__ bar)
{
    const int bid = blockIdx.x, tid = threadIdx.x;
    if (bid == 0){ bar[tid] = 0u; bar[128 + tid] = 0u; }   // 256 ctrs
    if (bid < NW){
        const int n = bid;
        const float* src = (n<512) ? Wv  + (size_t)n*512
                         : (n<768) ? Wg1 + (size_t)(n-512)*512
                         : (n<784) ? Wk  + (size_t)(n-768)*512
                         : (n<800) ? Wq  + (size_t)(n-784)*512
                         : (n<896) ? (const float*)0
                                   : Wo  + (size_t)(n-896)*512;
        float4 v = make_float4(0.f,0.f,0.f,0.f);
        if (src) v = ((const float4*)src)[tid];
        ushort4 o; o.x=f2bf(v.x); o.y=f2bf(v.y); o.z=f2bf(v.z); o.w=f2bf(v.w);
        ((ushort4*)(Wb + (size_t)n*512))[tid] = o;
        if (tid == 0)
            bcat[n] = (n<512)?bv[n] : (n<768)?bg1[n-512] : (n<784)?bk[n-768]
                    : (n<800)?bq[n-784] : (n<896)?0.f : bo[n-896];
    } else {
        const size_t i = (size_t)(bid - NW)*128 + tid;    // float4 index
        float4 v = ((const float4*)x)[i];
        ushort4 o; o.x=f2bf(v.x); o.y=f2bf(v.y); o.z=f2bf(v.z); o.w=f2bf(v.w);
        ((ushort4*)xb)[i] = o;
    }
}

// ---- device barrier, kernel-boundary-style: ONE L2 wb+inv per XCD ----
// slot layout: bar + slot*32: [0..7]=per-XCD arrive, [8]=done (leaders count)
// Correct because: __syncthreads drains vmcnt (stores are in local L2 before
// arrive); leader (first local arriver) flushes only after ALL 512 arrived;
// 512 blocks = exactly 2/CU (LDS-limited) so all 8 XCDs are active.
__device__ __forceinline__ void gsync(unsigned* bar, int slot, int xcc){
    __syncthreads();
    if (threadIdx.x == 0){
        unsigned* arr  = bar + slot*32;
        unsigned* done = arr + 8;
        const bool leader =
            (__hip_atomic_fetch_add(arr + xcc, 1u, __ATOMIC_RELAXED,
                                    __HIP_MEMORY_SCOPE_AGENT) == 0u);
        if (leader){
            for (;;){
                unsigned s = 0;
                #pragma unroll
                for (int i = 0; i < 8; ++i)
                    s += __hip_atomic_load(arr + i, __ATOMIC_RELAXED,
                                           __HIP_MEMORY_SCOPE_AGENT);
                if (s >= GRID_F) break;
                __builtin_amdgcn_s_sleep(1);
            }
            asm volatile("buffer_wbl2 sc1\n\t"
                         "s_waitcnt vmcnt(0)\n\t"
                         "buffer_inv sc0 sc1\n\t"
                         "s_waitcnt vmcnt(0)" ::: "memory");
            __hip_atomic_fetch_add(done, 1u, __ATOMIC_RELAXED,
                                   __HIP_MEMORY_SCOPE_AGENT);
        }
        while (__hip_atomic_load(done, __ATOMIC_RELAXED,
                                 __HIP_MEMORY_SCOPE_AGENT) < 8u)
            __builtin_amdgcn_s_sleep(1);
    }
    __syncthreads();
}

// ---- MFMA 64x64x512 tile core (verified) ----
__device__ __forceinline__ void gemm64x64(
    const unsigned short* Ag, const unsigned short* Bg,
    short* As, short* Bs, int tid, floatx4 acc[2][2])
{
    const int lane = tid & 63, w = tid >> 6;
    const int q = lane >> 4, m15 = lane & 15;
    for (int kt = 0; kt < 512; kt += 64) {
        __syncthreads();
        #pragma unroll
        for (int i = 0; i < 2; ++i) {
            const int rowbase = (w*2 + i) * 8;
            const int r  = rowbase + (lane >> 3);
            const int gb = (lane & 7) ^ (r & 7);
            const unsigned short* ga  = Ag + (size_t)r*512 + kt + gb*8;
            const unsigned short* gbp = Bg + (size_t)r*512 + kt + gb*8;
            __builtin_amdgcn_global_load_lds((cgu32*)(const void*)ga,
                                             (lu32*)(As + rowbase*64), 16, 0, 0);
            __builtin_amdgcn_global_load_lds((cgu32*)(const void*)gbp,
                                             (lu32*)(Bs + rowbase*64), 16, 0, 0);
        }
        __syncthreads();
        #pragma unroll
        for (int k32 = 0; k32 < 64; k32 += 32) {
            short8 af[2], bf[2];
            #pragma unroll
            for (int t = 0; t < 2; ++t) {
                const int ra  = 32*(w & 1) + 16*t + m15;
                const int sba = ((k32>>3) + q) ^ (ra & 7);
                af[t] = *(const short8*)(As + ra*64 + sba*8);
                const int rb  = 32*(w >> 1) + 16*t + m15;
                const int sbb = ((k32>>3) + q) ^ (rb & 7);
                bf[t] = *(const short8*)(Bs + rb*64 + sbb*8);
            }
            #pragma unroll
            for (int mt = 0; mt < 2; ++mt)
                #pragma unroll
                for (int nt = 0; nt < 2; ++nt)
                    acc[mt][nt] = __builtin_amdgcn_mfma_f32_16x16x32_bf16(
                        af[mt], bf[nt], acc[mt][nt], 0, 0, 0);
        }
    }
}

// ---- fused: GEMM1 -> act -> chunk sums -> prefix -> scan+LN -> GEMM2 ----
__global__ __launch_bounds__(256, 2) void k_fused(
    const unsigned short* __restrict__ xb, const unsigned short* __restrict__ Wb,
    const float* __restrict__ bcat, unsigned short* __restrict__ Vt,
    float* __restrict__ Yh,
    const float* __restrict__ Wg2, const float* __restrict__ bg2,
    const float* __restrict__ set_w, const float* __restrict__ pos_phases,
    const float* __restrict__ pos_weight,
    unsigned short* __restrict__ ab, unsigned short* __restrict__ Rb,
    unsigned short* __restrict__ aT,
    float* __restrict__ P, unsigned short* __restrict__ S0t,
    const float* __restrict__ ln_g, const float* __restrict__ ln_b,
    unsigned short* __restrict__ Tn,
    const float* __restrict__ x, float* __restrict__ out,
    unsigned* __restrict__ bar)
{
    __shared__ __align__(16) char smem[67584];   // max(As+Bs=16K, Msh+Tsh=66K)
    const int bid = blockIdx.x, tid = threadIdx.x;
    const int lane = tid & 63, w = tid >> 6;
    const int q = lane >> 4, m15 = lane & 15;
    int xcc;
    asm("s_getreg_b32 %0, hwreg(HW_REG_XCC_ID)" : "=s"(xcc));

    // ================= phase 1: GEMM1 (448 tiles) =================
    if (bid < 448){
        short* As = (short*)smem;
        short* Bs = (short*)(smem + 8192);
        const int row0 = (bid & 31)*64, n0 = (bid >> 5)*64;
        floatx4 acc[2][2];
        #pragma unroll
        for (int mt=0;mt<2;++mt)
            #pragma unroll
            for (int nt=0;nt<2;++nt) acc[mt][nt] = (floatx4){0.f,0.f,0.f,0.f};
        gemm64x64(xb + (size_t)row0*512, Wb + (size_t)n0*512, As, Bs, tid, acc);
        const int wm = w & 1, wn = w >> 1;
        if (n0 < 512){
            const int b = row0 >> 10, lb = row0 & 1023;
            #pragma unroll
            for (int mt=0;mt<2;++mt)
                #pragma unroll
                for (int nt=0;nt<2;++nt){
                    const int d = n0 + 32*wn + 16*nt + m15;
                    const float bb = bcat[d];
                    const int l0 = lb + 32*wm + 16*mt + q*4;
                    ushort4 o;
                    o.x = f2bf(acc[mt][nt][0] + bb);
                    o.y = f2bf(acc[mt][nt][1] + bb);
                    o.z = f2bf(acc[mt][nt][2] + bb);
                    o.w = f2bf(acc[mt][nt][3] + bb);
                    *(ushort4*)(Vt + ((size_t)(b*512 + d))*1024 + l0) = o;
                }
        } else {
            #pragma unroll
            for (int mt=0;mt<2;++mt)
                #pragma unroll
                for (int nt=0;nt<2;++nt){
                    const int n = n0 + 32*wn + 16*nt + m15;
                    const float bb = bcat[n];
                    #pragma unroll
                    for (int reg=0;reg<4;++reg){
                        const int m = row0 + 32*wm + 16*mt + q*4 + reg;
                        Yh[(size_t)m*YH + (n-512)] = acc[mt][nt][reg] + bb;
                    }
                }
        }
    }
    gsync(bar, 0, xcc);

    // ================= phase 2: activations (4 rows/block) =================
    {
        float s0=set_w[0], s1=set_w[1], s2=set_w[2], s3=set_w[3];
        float mm = fmaxf(fmaxf(s0,s1), fmaxf(s2,s3));
        float e0=expf(s0-mm), e1=expf(s1-mm), e2=expf(s2-mm), e3=expf(s3-mm);
        float esum = e0+e1+e2+e3;
        float spw = 1.f/(1.f+expf(-pos_weight[0]));
        float b2 = bg2[0];
        const int row = bid*4 + w;
        const float* yrow = Yh + (size_t)row*YH;
        float hs = 0.f;
        #pragma unroll
        for (int i=0;i<4;++i){
            float hv = yrow[lane + 64*i];
            float ge = 0.5f*hv*(1.f + erff(hv*0.70710678118f));
            hs += ge * Wg2[lane + 64*i];
        }
        #pragma unroll
        for (int off=32; off; off>>=1) hs += __shfl_xor(hs, off, 64);
        float g = 1.f/(1.f+expf(-(hs + b2)));
        if (lane < 16){
            int j = lane;
            int l = row & (LL-1);
            int b = row >> 10;
            float kang = PI_F*tanhf(yrow[256 + j]);
            float qang = PI_F*tanhf(yrow[272 + j]);
            float wsm = (j<4?e0: j<8?e1: j<12?e2: e3) / esum;
            float rnorm = 1.f/(2.f*sqrtf((float)(l+1)));
            float av[4], rv[4];
            av[0] = cosf(kang); av[1] = sinf(kang);
            float cw = g*wsm*rnorm;
            rv[0] = cw*cosf(qang); rv[1] = cw*sinf(qang);
            float ph = pos_phases[(size_t)l*16 + j];
            float pc = cosf(ph), ps = sinf(ph);
            av[2] = pc; av[3] = ps;
            float cp = (1.f-g)*spw*rnorm;
            rv[2] = cp*pc; rv[3] = cp*ps;
            unsigned short* arow = ab + (size_t)row*NCH;
            unsigned short* Rrow = Rb + (size_t)row*NCH;
            #pragma unroll
            for (int t=0;t<4;++t){
                arow[16*t + j] = f2bf(av[t]);
                Rrow[16*t + j] = f2bf(rv[t]);
                aT[((size_t)b*NCH + 16*t + j)*1024 + l] = f2bf(av[t]);
            }
        }
    }
    gsync(bar, 1, xcc);

    // ================= phase 3: chunk sums (all 512 blocks, d split 8-way) ===
    {
        const int c = bid & 31, b = (bid >> 5) & 1, z8 = bid >> 6;
        short8 af[4];
        #pragma unroll
        for (int mt=0;mt<4;++mt)
            af[mt] = *(const short8*)(aT + ((size_t)b*NCH + 16*mt + m15)*1024 + c*32 + q*8);
        const int d = z8*64 + w*16 + m15;
        short8 bf = *(const short8*)(Vt + ((size_t)(b*512 + d))*1024 + c*32 + q*8);
        floatx4 pacc[4];
        #pragma unroll
        for (int mt=0;mt<4;++mt) pacc[mt] = (floatx4){0.f,0.f,0.f,0.f};
        #pragma unroll
        for (int mt=0;mt<4;++mt)
            pacc[mt] = __builtin_amdgcn_mfma_f32_16x16x32_bf16(af[mt], bf, pacc[mt], 0,0,0);
        float* Pc = P + ((size_t)(b*NCHUNK + c))*512*NCH;
        #pragma unroll
        for (int mt=0;mt<4;++mt)
            *(floatx4*)(Pc + (size_t)d*NCH + 16*mt + q*4) = pacc[mt];
    }
    gsync(bar, 2, xcc);

    // ================= phase 4: exclusive prefix over chunks =================
    if (bid < 256){
        const int b = bid >> 7;
        const size_t idx = (size_t)(bid & 127)*256 + tid;   // over 512*64
        float run = 0.f;
        for (int c2=0;c2<NCHUNK;++c2){
            const size_t o = ((size_t)(b*NCHUNK + c2))*512*NCH + idx;
            float v = P[o];
            S0t[o] = f2bf(run);
            run += v;
        }
    }
    gsync(bar, 3, xcc);

    // ================= phase 5: within-chunk scan + LN =================
    if (bid < 64){
        short* Msh = (short*)smem;            // 32*32 shorts
        float* Tsh = (float*)(smem + 2048);   // 32*512 floats
        const int c = bid & 31, b = bid >> 5;
        const int grow = b*1024 + c*32;

        if (w == 0){                       // wave 0 computes M = tril(R @ a^T)
            floatx4 mcc[2][2];
            #pragma unroll
            for (int mt=0;mt<2;++mt)
                #pragma unroll
                for (int nt=0;nt<2;++nt) mcc[mt][nt] = (floatx4){0.f,0.f,0.f,0.f};
            #pragma unroll
            for (int ks=0;ks<2;++ks){
                short8 ra[2], bb[2];
                #pragma unroll
                for (int t=0;t<2;++t){
                    ra[t] = *(const short8*)(Rb + (size_t)(grow + 16*t + m15)*NCH + ks*32 + q*8);
                    bb[t] = *(const short8*)(ab + (size_t)(grow + 16*t + m15)*NCH + ks*32 + q*8);
                }
                #pragma unroll
                for (int mt=0;mt<2;++mt)
                    #pragma unroll
                    for (int nt=0;nt<2;++nt)
                        mcc[mt][nt] = __builtin_amdgcn_mfma_f32_16x16x32_bf16(
                            ra[mt], bb[nt], mcc[mt][nt], 0,0,0);
            }
            #pragma unroll
            for (int mt=0;mt<2;++mt)
                #pragma unroll
                for (int nt=0;nt<2;++nt){
                    const int nl = 16*nt + m15;
                    #pragma unroll
                    for (int reg=0;reg<4;++reg){
                        const int ml = 16*mt + q*4 + reg;
                        Msh[ml*32 + nl] = (nl <= ml) ? (short)f2bf(mcc[mt][nt][reg]) : (short)0;
                    }
                }
        }
        __syncthreads();

        short8 a1[2], a2[2][2];
        #pragma unroll
        for (int mt=0;mt<2;++mt){
            a1[mt] = *(const short8*)(Msh + (16*mt + m15)*32 + q*8);
            #pragma unroll
            for (int ks=0;ks<2;++ks)
                a2[ks][mt] = *(const short8*)(Rb + (size_t)(grow + 16*mt + m15)*NCH + ks*32 + q*8);
        }
        floatx4 acc[2][8];
        #pragma unroll
        for (int mt=0;mt<2;++mt)
            #pragma unroll
            for (int nt=0;nt<8;++nt) acc[mt][nt] = (floatx4){0.f,0.f,0.f,0.f};
        const unsigned short* S0c = S0t + ((size_t)(b*NCHUNK + c))*512*NCH;
        #pragma unroll
        for (int nt=0;nt<8;++nt){
            const int d = w*128 + 16*nt + m15;
            short8 b1 = *(const short8*)(Vt + ((size_t)(b*512 + d))*1024 + c*32 + q*8);
            #pragma unroll
            for (int mt=0;mt<2;++mt)
                acc[mt][nt] = __builtin_amdgcn_mfma_f32_16x16x32_bf16(a1[mt], b1, acc[mt][nt], 0,0,0);
            #pragma unroll
            for (int ks=0;ks<2;++ks){
                short8 b2v = *(const short8*)(S0c + (size_t)d*NCH + ks*32 + q*8);
                #pragma unroll
                for (int mt=0;mt<2;++mt)
                    acc[mt][nt] = __builtin_amdgcn_mfma_f32_16x16x32_bf16(a2[ks][mt], b2v, acc[mt][nt], 0,0,0);
            }
        }
        #pragma unroll
        for (int mt=0;mt<2;++mt)
            #pragma unroll
            for (int nt=0;nt<8;++nt){
                const int d = w*128 + 16*nt + m15;
                #pragma unroll
                for (int reg=0;reg<4;++reg)
                    Tsh[(16*mt + q*4 + reg)*512 + d] = acc[mt][nt][reg];
            }
        __syncthreads();

        // LN per row (wave handles 8 rows), write Tn bf16 row-major
        #pragma unroll
        for (int i=0;i<8;++i){
            const int r = w*8 + i;
            float s=0.f, sq=0.f;
            #pragma unroll
            for (int t=0;t<8;++t){
                float v = Tsh[r*512 + lane + 64*t];
                s += v; sq += v*v;
            }
            #pragma unroll
            for (int off=32; off; off>>=1){
                s += __shfl_xor(s, off, 64); sq += __shfl_xor(sq, off, 64);
            }
            float mu  = s*(1.f/512.f);
            float var = sq*(1.f/512.f) - mu*mu;
            float rsd = rsqrtf(var + 1e-5f);
            unsigned short* trow = Tn + (size_t)(grow + r)*512;
            #pragma unroll
            for (int t=0;t<8;++t){
                const int d = lane + 64*t;
                float v = (Tsh[r*512 + d] - mu)*rsd*ln_g[d] + ln_b[d];
                trow[d] = f2bf(v);
            }
        }
    }
    gsync(bar, 4, xcc);

    // ================= phase 6: GEMM2 (256 tiles) =================
    if (bid < 256){
        short* As = (short*)smem;
        short* Bs = (short*)(smem + 8192);
        const int row0 = (bid & 31)*64, n0 = (bid >> 5)*64;
        floatx4 acc[2][2];
        #pragma unroll
        for (int mt=0;mt<2;++mt)
            #pragma unroll
            for (int nt=0;nt<2;++nt) acc[mt][nt] = (floatx4){0.f,0.f,0.f,0.f};
        gemm64x64(Tn + (size_t)row0*512, Wb + (size_t)(896+n0)*512, As, Bs, tid, acc);
        const int wm = w & 1, wn = w >> 1;
        #pragma unroll
        for (int mt=0;mt<2;++mt)
            #pragma unroll
            for (int nt=0;nt<2;++nt){
                const int n = n0 + 32*wn + 16*nt + m15;
                const float bb = bcat[896 + n];
                #pragma unroll
                for (int reg=0;reg<4;++reg){
                    const int m = row0 + 32*wm + 16*mt + q*4 + reg;
                    out[(size_t)m*512 + n] = x[(size_t)m*512 + n] + acc[mt][nt][reg] + bb;
                }
            }
    }
}

extern "C" void kernel_launch(void* const* d_in, const int* in_sizes, int n_in,
                              void* d_out, int out_size, void* d_ws, size_t ws_size,
                              hipStream_t stream) {
    const float* x    = (const float*)d_in[0];
    const float* Wk   = (const float*)d_in[1];
    const float* bk   = (const float*)d_in[2];
    const float* Wq   = (const float*)d_in[3];
    const float* bq   = (const float*)d_in[4];
    const float* Wv   = (const float*)d_in[5];
    const float* bv   = (const float*)d_in[6];
    const float* ln_g = (const float*)d_in[7];
    const float* ln_b = (const float*)d_in[8];
    const float* Wo   = (const float*)d_in[9];
    const float* bo   = (const float*)d_in[10];
    const float* set_w      = (const float*)d_in[11];
    const float* pos_phases = (const float*)d_in[12];
    const float* pos_weight = (const float*)d_in[13];
    const float* Wg1  = (const float*)d_in[14];
    const float* bg1  = (const float*)d_in[15];
    const float* Wg2  = (const float*)d_in[16];
    const float* bg2  = (const float*)d_in[17];
    float* out = (float*)d_out;

    // workspace: fp32 region, then bf16 region (~24 MB), then barrier ctrs
    float* ws   = (float*)d_ws;
    float* Yh   = ws;                                     // 2048*384
    float* P    = Yh + (size_t)2048*YH;                   // 2*32*512*64
    float* bcat = P  + (size_t)BB*NCHUNK*512*NCH;         // 1408
    unsigned short* Wb  = (unsigned short*)(bcat + NW);   // 1408*512
    unsigned short* xb  = Wb  + (size_t)NW*512;           // 2048*512
    unsigned short* Vt  = xb  + (size_t)2048*512;         // 2*512*1024
    unsigned short* ab  = Vt  + (size_t)BB*512*1024;      // 2048*64
    unsigned short* Rb  = ab  + (size_t)2048*NCH;         // 2048*64
    unsigned short* aT  = Rb  + (size_t)2048*NCH;         // 2*64*1024
    unsigned short* S0t = aT  + (size_t)BB*NCH*1024;      // 2*32*512*64
    unsigned short* Tn  = S0t + (size_t)BB*NCHUNK*512*NCH;// 2048*512
    unsigned*       bar = (unsigned*)(Tn + (size_t)2048*512); // 256 ctrs

    k_prep<<<dim3(NW + 2048), 128, 0, stream>>>(
        Wv,Wg1,Wk,Wq,Wo, bv,bg1,bk,bq,bo, x, Wb, bcat, xb, bar);
    k_fused<<<dim3(GRID_F), 256, 0, stream>>>(
        xb, Wb, bcat, Vt, Yh, Wg2, bg2, set_w, pos_phases, pos_weight,
        ab, Rb, aT, P, S0t, ln_g, ln_b, Tn, x, out, bar);
}